// Round 1
// baseline (413.829 us; speedup 1.0000x reference)
//
#include <hip/hip_runtime.h>
#include <math.h>

#define DEVINL __device__ __forceinline__

DEVINL float sigm(float x) { return 1.0f / (1.0f + __expf(-x)); }
DEVINL float tanh_(float x) { return 2.0f / (1.0f + __expf(-2.0f * x)) - 1.0f; }

// ---------------------------------------------------------------------------
// Kernel 1: node LSTM. B=256, T=8, In=2, H=64, collect=True.
// One block per batch element, 256 threads = gate rows. Whh row in registers.
// ---------------------------------------------------------------------------
__global__ __launch_bounds__(256) void node_lstm_k(
    const float* __restrict__ scene,  // [256][8][2]
    const float* __restrict__ Wih,    // [256][2]
    const float* __restrict__ Whh,    // [256][64]
    const float* __restrict__ bih, const float* __restrict__ bhh,
    float* __restrict__ out)          // [256][8][64]
{
    const int b = blockIdx.x;
    const int t = threadIdx.x;   // gate row 0..255
    __shared__ __align__(16) float lds_h[64];
    __shared__ float lds_g[256];

    float whh[64];
#pragma unroll
    for (int k = 0; k < 64; k += 4) {
        float4 v = *reinterpret_cast<const float4*>(&Whh[t * 64 + k]);
        whh[k] = v.x; whh[k+1] = v.y; whh[k+2] = v.z; whh[k+3] = v.w;
    }
    const float wx = Wih[2*t], wy = Wih[2*t + 1];
    const float bias = bih[t] + bhh[t];
    float c = 0.0f;
    if (t < 64) lds_h[t] = 0.0f;
    __syncthreads();

#pragma unroll 1
    for (int step = 0; step < 8; ++step) {
        const float x0 = scene[b*16 + step*2 + 0];
        const float x1 = scene[b*16 + step*2 + 1];
        float acc = wx * x0 + wy * x1 + bias;
#pragma unroll
        for (int k = 0; k < 64; k += 4) {
            float4 h4 = *reinterpret_cast<const float4*>(&lds_h[k]);
            acc += whh[k]*h4.x + whh[k+1]*h4.y + whh[k+2]*h4.z + whh[k+3]*h4.w;
        }
        const float gv = ((t >> 6) == 2) ? tanh_(acc) : sigm(acc);
        lds_g[t] = gv;
        __syncthreads();
        if (t < 64) {
            const float gi = lds_g[t], gf = lds_g[64+t], gc = lds_g[128+t], go = lds_g[192+t];
            c = gf * c + gi * gc;
            const float h = go * tanh_(c);
            lds_h[t] = h;
            out[(b*8 + step)*64 + t] = h;
        }
        __syncthreads();
    }
}

// ---------------------------------------------------------------------------
// Kernel 2: edge LSTM (the heavy one). B=2048 (=i*8+s), T=256 (neighbor j),
// In=2 computed on the fly: x_j = scene[j,s] - scene[i,s]. collect=False.
// ---------------------------------------------------------------------------
__global__ __launch_bounds__(256) void edge_lstm_k(
    const float* __restrict__ scene,  // [256][8][2]
    const float* __restrict__ Wih,    // [256][2]
    const float* __restrict__ Whh,    // [256][64]
    const float* __restrict__ bih, const float* __restrict__ bhh,
    float* __restrict__ dist_hist)    // [2048][64] = [256][8][64]
{
    const int blk = blockIdx.x;
    const int i = blk >> 3, s = blk & 7;
    const int t = threadIdx.x;
    __shared__ __align__(16) float lds_h[64];
    __shared__ float lds_g[256];
    __shared__ float2 lds_sc[256];   // scene[:, s, :]

    float whh[64];
#pragma unroll
    for (int k = 0; k < 64; k += 4) {
        float4 v = *reinterpret_cast<const float4*>(&Whh[t * 64 + k]);
        whh[k] = v.x; whh[k+1] = v.y; whh[k+2] = v.z; whh[k+3] = v.w;
    }
    const float wx = Wih[2*t], wy = Wih[2*t + 1];
    const float bias = bih[t] + bhh[t];

    // stage scene[:, s, :] (one float2 per thread, one-time)
    lds_sc[t] = make_float2(scene[t*16 + s*2 + 0], scene[t*16 + s*2 + 1]);
    if (t < 64) lds_h[t] = 0.0f;
    const float cx0 = scene[i*16 + s*2 + 0];
    const float cy0 = scene[i*16 + s*2 + 1];
    float c = 0.0f;
    __syncthreads();

#pragma unroll 1
    for (int j = 0; j < 256; ++j) {
        const float2 sc = lds_sc[j];
        const float dx = sc.x - cx0, dy = sc.y - cy0;
        float acc = wx * dx + wy * dy + bias;
#pragma unroll
        for (int k = 0; k < 64; k += 4) {
            float4 h4 = *reinterpret_cast<const float4*>(&lds_h[k]);
            acc += whh[k]*h4.x + whh[k+1]*h4.y + whh[k+2]*h4.z + whh[k+3]*h4.w;
        }
        const float gv = ((t >> 6) == 2) ? tanh_(acc) : sigm(acc);
        lds_g[t] = gv;
        __syncthreads();
        if (t < 64) {
            const float gi = lds_g[t], gf = lds_g[64+t], gc = lds_g[128+t], go = lds_g[192+t];
            c = gf * c + gi * gc;
            lds_h[t] = go * tanh_(c);
        }
        __syncthreads();
    }
    if (t < 64) dist_hist[blk*64 + t] = lds_h[t];
}

// ---------------------------------------------------------------------------
// Kernel 3: seq LSTM. B=256, T=8, In=64 (dist_hist), H=64, collect=True.
// ---------------------------------------------------------------------------
__global__ __launch_bounds__(256) void seq_lstm_k(
    const float* __restrict__ dist_hist,  // [256][8][64]
    const float* __restrict__ Wih,        // [256][64]
    const float* __restrict__ Whh,        // [256][64]
    const float* __restrict__ bih, const float* __restrict__ bhh,
    float* __restrict__ out)              // [256][8][64]
{
    const int b = blockIdx.x;
    const int t = threadIdx.x;
    __shared__ __align__(16) float lds_h[64];
    __shared__ __align__(16) float lds_x[64];
    __shared__ float lds_g[256];

    float whh[64], wih[64];
#pragma unroll
    for (int k = 0; k < 64; k += 4) {
        float4 v = *reinterpret_cast<const float4*>(&Whh[t * 64 + k]);
        whh[k] = v.x; whh[k+1] = v.y; whh[k+2] = v.z; whh[k+3] = v.w;
        float4 w = *reinterpret_cast<const float4*>(&Wih[t * 64 + k]);
        wih[k] = w.x; wih[k+1] = w.y; wih[k+2] = w.z; wih[k+3] = w.w;
    }
    const float bias = bih[t] + bhh[t];
    float c = 0.0f;
    if (t < 64) lds_h[t] = 0.0f;
    __syncthreads();

#pragma unroll 1
    for (int step = 0; step < 8; ++step) {
        if (t < 64) lds_x[t] = dist_hist[(b*8 + step)*64 + t];
        __syncthreads();
        float acc = bias;
#pragma unroll
        for (int k = 0; k < 64; k += 4) {
            float4 h4 = *reinterpret_cast<const float4*>(&lds_h[k]);
            float4 x4 = *reinterpret_cast<const float4*>(&lds_x[k]);
            acc += whh[k]*h4.x + whh[k+1]*h4.y + whh[k+2]*h4.z + whh[k+3]*h4.w;
            acc += wih[k]*x4.x + wih[k+1]*x4.y + wih[k+2]*x4.z + wih[k+3]*x4.w;
        }
        const float gv = ((t >> 6) == 2) ? tanh_(acc) : sigm(acc);
        lds_g[t] = gv;
        __syncthreads();
        if (t < 64) {
            const float gi = lds_g[t], gf = lds_g[64+t], gc = lds_g[128+t], go = lds_g[192+t];
            c = gf * c + gi * gc;
            const float h = go * tanh_(c);
            lds_h[t] = h;
            out[(b*8 + step)*64 + t] = h;
        }
        __syncthreads();
    }
}

// ---------------------------------------------------------------------------
// Kernel 4: decoder LSTM (In=128 = concat(lstm_out, full_dist), H=EMB=32,
// T=8) fused with the pose head. Block = 128 threads (gate rows), grid 256.
// ---------------------------------------------------------------------------
__global__ __launch_bounds__(128) void dec_lstm_k(
    const float* __restrict__ lstm_out,   // [256][8][64]
    const float* __restrict__ full_dist,  // [256][8][64]
    const float* __restrict__ scene,      // [256][8][2]
    const float* __restrict__ Wih,        // [128][128]
    const float* __restrict__ Whh,        // [128][32]
    const float* __restrict__ bih, const float* __restrict__ bhh,
    const float* __restrict__ pose_W,     // [2][256]
    const float* __restrict__ pose_b,     // [2]
    float* __restrict__ out)              // [256][1][2]
{
    const int b = blockIdx.x;
    const int t = threadIdx.x;  // 0..127
    __shared__ __align__(16) float lds_h[32];
    __shared__ __align__(16) float lds_x[128];
    __shared__ float lds_g[128];
    __shared__ float lds_dec[8][32];

    float wih[128];
#pragma unroll
    for (int k = 0; k < 128; k += 4) {
        float4 w = *reinterpret_cast<const float4*>(&Wih[t * 128 + k]);
        wih[k] = w.x; wih[k+1] = w.y; wih[k+2] = w.z; wih[k+3] = w.w;
    }
    float whh[32];
#pragma unroll
    for (int k = 0; k < 32; k += 4) {
        float4 v = *reinterpret_cast<const float4*>(&Whh[t * 32 + k]);
        whh[k] = v.x; whh[k+1] = v.y; whh[k+2] = v.z; whh[k+3] = v.w;
    }
    const float bias = bih[t] + bhh[t];
    float c = 0.0f;
    if (t < 32) lds_h[t] = 0.0f;
    __syncthreads();

#pragma unroll 1
    for (int step = 0; step < 8; ++step) {
        if (t < 64) lds_x[t] = lstm_out[(b*8 + step)*64 + t];
        else        lds_x[t] = full_dist[(b*8 + step)*64 + (t - 64)];
        __syncthreads();
        float acc = bias;
#pragma unroll
        for (int k = 0; k < 128; k += 4) {
            float4 x4 = *reinterpret_cast<const float4*>(&lds_x[k]);
            acc += wih[k]*x4.x + wih[k+1]*x4.y + wih[k+2]*x4.z + wih[k+3]*x4.w;
        }
#pragma unroll
        for (int k = 0; k < 32; k += 4) {
            float4 h4 = *reinterpret_cast<const float4*>(&lds_h[k]);
            acc += whh[k]*h4.x + whh[k+1]*h4.y + whh[k+2]*h4.z + whh[k+3]*h4.w;
        }
        const float gv = ((t >> 5) == 2) ? tanh_(acc) : sigm(acc);
        lds_g[t] = gv;
        __syncthreads();
        if (t < 32) {
            const float gi = lds_g[t], gf = lds_g[32+t], gc = lds_g[64+t], go = lds_g[96+t];
            c = gf * c + gi * gc;
            const float h = go * tanh_(c);
            lds_h[t] = h;
            lds_dec[step][t] = h;
        }
        __syncthreads();
    }

    // pose head: tag[d] = scene[b,7,d] + sum_q dec_r[q] * pose_W[d][q] + pose_b[d]
    if (t < 2) {
        const float* dec_flat = &lds_dec[0][0];
        float acc = scene[b*16 + 14 + t] + pose_b[t];
        for (int q = 0; q < 256; ++q)
            acc += dec_flat[q] * pose_W[t*256 + q];
        out[b*2 + t] = acc;
    }
}

// ---------------------------------------------------------------------------
extern "C" void kernel_launch(void* const* d_in, const int* in_sizes, int n_in,
                              void* d_out, int out_size, void* d_ws, size_t ws_size,
                              hipStream_t stream) {
    const float* scene    = (const float*)d_in[0];
    const float* node_Wih = (const float*)d_in[1];
    const float* node_Whh = (const float*)d_in[2];
    const float* node_bih = (const float*)d_in[3];
    const float* node_bhh = (const float*)d_in[4];
    const float* edge_Wih = (const float*)d_in[5];
    const float* edge_Whh = (const float*)d_in[6];
    const float* edge_bih = (const float*)d_in[7];
    const float* edge_bhh = (const float*)d_in[8];
    const float* seq_Wih  = (const float*)d_in[9];
    const float* seq_Whh  = (const float*)d_in[10];
    const float* seq_bih  = (const float*)d_in[11];
    const float* seq_bhh  = (const float*)d_in[12];
    const float* dec_Wih  = (const float*)d_in[13];
    const float* dec_Whh  = (const float*)d_in[14];
    const float* dec_bih  = (const float*)d_in[15];
    const float* dec_bhh  = (const float*)d_in[16];
    const float* pose_W   = (const float*)d_in[17];
    const float* pose_b   = (const float*)d_in[18];
    float* out = (float*)d_out;

    float* ws = (float*)d_ws;
    float* lstm_out  = ws;               // 256*8*64
    float* dist_hist = ws + 131072;      // 256*8*64
    float* full_dist = ws + 262144;      // 256*8*64

    node_lstm_k<<<256, 256, 0, stream>>>(scene, node_Wih, node_Whh, node_bih, node_bhh, lstm_out);
    edge_lstm_k<<<2048, 256, 0, stream>>>(scene, edge_Wih, edge_Whh, edge_bih, edge_bhh, dist_hist);
    seq_lstm_k<<<256, 256, 0, stream>>>(dist_hist, seq_Wih, seq_Whh, seq_bih, seq_bhh, full_dist);
    dec_lstm_k<<<256, 128, 0, stream>>>(lstm_out, full_dist, scene, dec_Wih, dec_Whh,
                                        dec_bih, dec_bhh, pose_W, pose_b, out);
}

// Round 2
// 172.986 us; speedup vs baseline: 2.3923x; 2.3923x over previous
//
#include <hip/hip_runtime.h>
#include <math.h>

#define DEVINL __device__ __forceinline__

typedef __attribute__((ext_vector_type(8))) short bf16x8;
typedef __attribute__((ext_vector_type(4))) float f32x4;

DEVINL float sigm(float x) { return __builtin_amdgcn_rcpf(1.0f + __expf(-x)); }
DEVINL float tanh_(float x) { return fmaf(2.0f, __builtin_amdgcn_rcpf(1.0f + __expf(-2.0f * x)), -1.0f); }

DEVINL unsigned short f2bf(float f) {
    union { float f; unsigned u; } v; v.f = f;
    unsigned r = v.u + 0x7FFFu + ((v.u >> 16) & 1u);   // RNE
    return (unsigned short)(r >> 16);
}

DEVINL bf16x8 pack8(const float* p) {
    bf16x8 r;
#pragma unroll
    for (int e = 0; e < 8; ++e) r[e] = (short)f2bf(p[e]);
    return r;
}

// ---------------------------------------------------------------------------
// Edge LSTM via MFMA. Block = 16 sequences (2 persons x 8 timesteps),
// 256 threads = 4 waves. Per step j (neighbor axis, T=256):
//   G[256x16] = Whh[256x64] @ H[64x16]  (bf16 MFMA, fp32 acc)
//   Cinit     = bias + Wih @ (scene[j,s] - scene[i,s])   (VALU, rank-2)
// Wave w owns gate-tiles {i,f,g,o} x u-group [16w,16w+16): cell update is
// register-local. h exchanged via XOR-swizzled double-buffered LDS (bf16).
// ---------------------------------------------------------------------------
__global__ __launch_bounds__(256, 1) void edge_lstm_mfma_k(
    const float* __restrict__ scene,  // [256][8][2]
    const float* __restrict__ Wih,    // [256][2]
    const float* __restrict__ Whh,    // [256][64]
    const float* __restrict__ bih, const float* __restrict__ bhh,
    float* __restrict__ dist_hist)    // [2048][64]
{
    const int b  = blockIdx.x;     // 0..127
    const int t  = threadIdx.x;    // 0..255
    const int w  = t >> 6;         // wave 0..3 -> u-group
    const int l  = t & 63;
    const int n  = l & 15;         // sequence within block
    const int lg = l >> 4;         // 0..3
    const int s_n = n & 7;         // timestep of this seq
    const int i_n = 2 * b + (n >> 3);

    __shared__ __align__(16) float  lds_scene[256 * 16];     // 16 KB: [j][s][2]
    __shared__ __align__(16) unsigned short hbuf[2][16 * 64]; // 2 x 2 KB, [n][k] bf16 swizzled

    // ---- stage scene (coalesced), zero h buffer 0 ----
    {
        const float4* src = reinterpret_cast<const float4*>(scene);
        float4* dst = reinterpret_cast<float4*>(lds_scene);
#pragma unroll
        for (int k = 0; k < 4; ++k) dst[k * 256 + t] = src[k * 256 + t];
        uint2* z = reinterpret_cast<uint2*>(&hbuf[0][0]);
        z[t] = make_uint2(0u, 0u);
    }

    // ---- preload A fragments: Whh rows for tiles q (gate) x kt (K half) ----
    // A layout: lane holds row (l&15) of the 16-row tile, k = lg*8 + e + 32*kt
    bf16x8 afrag[4][2];
#pragma unroll
    for (int q = 0; q < 4; ++q) {
        const int arow = 64 * q + 16 * w + (l & 15);
#pragma unroll
        for (int kt = 0; kt < 2; ++kt) {
            float tmp[8];
            float4 v0 = *reinterpret_cast<const float4*>(&Whh[arow * 64 + kt * 32 + lg * 8]);
            float4 v1 = *reinterpret_cast<const float4*>(&Whh[arow * 64 + kt * 32 + lg * 8 + 4]);
            tmp[0]=v0.x; tmp[1]=v0.y; tmp[2]=v0.z; tmp[3]=v0.w;
            tmp[4]=v1.x; tmp[5]=v1.y; tmp[6]=v1.z; tmp[7]=v1.w;
            afrag[q][kt] = pack8(tmp);
        }
    }

    // ---- per-lane C-side constants: gate rows g = 64q + 16w + 4*lg + r ----
    float O[4][4], wxr[4][4], wyr[4][4];
#pragma unroll
    for (int q = 0; q < 4; ++q)
#pragma unroll
        for (int r = 0; r < 4; ++r) {
            const int g = 64 * q + 16 * w + 4 * lg + r;
            wxr[q][r] = Wih[2 * g];
            wyr[q][r] = Wih[2 * g + 1];
            O[q][r]   = bih[g] + bhh[g];
        }
    const float sxi = scene[i_n * 16 + s_n * 2 + 0];
    const float syi = scene[i_n * 16 + s_n * 2 + 1];

    // LDS addressing (byte offsets, XOR swizzle on bits 4-6 by n&7)
    const int swz = (n & 7) << 4;
    const int rd0 = n * 128 + ((16 * lg) ^ swz);            // B frag kt=0; kt=1 = rd0^64
    const int wrb = n * 128 + (((32 * w) + 8 * lg) ^ swz);  // h write (4 u's, 8B)

    float c[4] = {0.f, 0.f, 0.f, 0.f};
    float h[4] = {0.f, 0.f, 0.f, 0.f};
    int cur = 0;
    __syncthreads();

#pragma unroll 1
    for (int j = 0; j < 256; ++j) {
        const char* hb = reinterpret_cast<const char*>(&hbuf[0][0]) + cur * 2048;
        bf16x8 b0 = *reinterpret_cast<const bf16x8*>(hb + rd0);
        bf16x8 b1 = *reinterpret_cast<const bf16x8*>(hb + (rd0 ^ 64));
        float2 sc = *reinterpret_cast<const float2*>(&lds_scene[j * 16 + s_n * 2]);
        const float dx = sc.x - sxi, dy = sc.y - syi;

        f32x4 acc[4];
#pragma unroll
        for (int q = 0; q < 4; ++q)
#pragma unroll
            for (int r = 0; r < 4; ++r)
                acc[q][r] = fmaf(wyr[q][r], dy, fmaf(wxr[q][r], dx, O[q][r]));

#pragma unroll
        for (int q = 0; q < 4; ++q) {
            acc[q] = __builtin_amdgcn_mfma_f32_16x16x32_bf16(afrag[q][0], b0, acc[q], 0, 0, 0);
            acc[q] = __builtin_amdgcn_mfma_f32_16x16x32_bf16(afrag[q][1], b1, acc[q], 0, 0, 0);
        }

#pragma unroll
        for (int r = 0; r < 4; ++r) {
            const float gi = sigm(acc[0][r]);
            const float gf = sigm(acc[1][r]);
            const float gg = tanh_(acc[2][r]);
            const float go = sigm(acc[3][r]);
            c[r] = fmaf(gf, c[r], gi * gg);
            h[r] = go * tanh_(c[r]);
        }

        const unsigned lo = (unsigned)f2bf(h[0]) | ((unsigned)f2bf(h[1]) << 16);
        const unsigned hi = (unsigned)f2bf(h[2]) | ((unsigned)f2bf(h[3]) << 16);
        char* hw = reinterpret_cast<char*>(&hbuf[0][0]) + (cur ^ 1) * 2048;
        *reinterpret_cast<uint2*>(hw + wrb) = make_uint2(lo, hi);

        __syncthreads();
        cur ^= 1;
    }

    // final h -> dist_hist[seq][u], seq = 16b + n, u = 16w + 4*lg + r
    float4 hv; hv.x = h[0]; hv.y = h[1]; hv.z = h[2]; hv.w = h[3];
    *reinterpret_cast<float4*>(&dist_hist[(16 * b + n) * 64 + 16 * w + 4 * lg]) = hv;
}

// ---------------------------------------------------------------------------
// Kernel 1: node LSTM (unchanged). B=256, T=8, In=2, H=64.
// ---------------------------------------------------------------------------
__global__ __launch_bounds__(256) void node_lstm_k(
    const float* __restrict__ scene, const float* __restrict__ Wih,
    const float* __restrict__ Whh, const float* __restrict__ bih,
    const float* __restrict__ bhh, float* __restrict__ out)
{
    const int b = blockIdx.x;
    const int t = threadIdx.x;
    __shared__ __align__(16) float lds_h[64];
    __shared__ float lds_g[256];

    float whh[64];
#pragma unroll
    for (int k = 0; k < 64; k += 4) {
        float4 v = *reinterpret_cast<const float4*>(&Whh[t * 64 + k]);
        whh[k] = v.x; whh[k+1] = v.y; whh[k+2] = v.z; whh[k+3] = v.w;
    }
    const float wx = Wih[2*t], wy = Wih[2*t + 1];
    const float bias = bih[t] + bhh[t];
    float c = 0.0f;
    if (t < 64) lds_h[t] = 0.0f;
    __syncthreads();

#pragma unroll 1
    for (int step = 0; step < 8; ++step) {
        const float x0 = scene[b*16 + step*2 + 0];
        const float x1 = scene[b*16 + step*2 + 1];
        float acc = wx * x0 + wy * x1 + bias;
#pragma unroll
        for (int k = 0; k < 64; k += 4) {
            float4 h4 = *reinterpret_cast<const float4*>(&lds_h[k]);
            acc += whh[k]*h4.x + whh[k+1]*h4.y + whh[k+2]*h4.z + whh[k+3]*h4.w;
        }
        const float gv = ((t >> 6) == 2) ? (2.0f / (1.0f + __expf(-2.0f*acc)) - 1.0f)
                                         : (1.0f / (1.0f + __expf(-acc)));
        lds_g[t] = gv;
        __syncthreads();
        if (t < 64) {
            const float gi = lds_g[t], gf = lds_g[64+t], gc = lds_g[128+t], go = lds_g[192+t];
            c = gf * c + gi * gc;
            const float h = go * (2.0f / (1.0f + __expf(-2.0f*c)) - 1.0f);
            lds_h[t] = h;
            out[(b*8 + step)*64 + t] = h;
        }
        __syncthreads();
    }
}

// ---------------------------------------------------------------------------
// Kernel 3: seq LSTM (unchanged). B=256, T=8, In=64, H=64.
// ---------------------------------------------------------------------------
__global__ __launch_bounds__(256) void seq_lstm_k(
    const float* __restrict__ dist_hist, const float* __restrict__ Wih,
    const float* __restrict__ Whh, const float* __restrict__ bih,
    const float* __restrict__ bhh, float* __restrict__ out)
{
    const int b = blockIdx.x;
    const int t = threadIdx.x;
    __shared__ __align__(16) float lds_h[64];
    __shared__ __align__(16) float lds_x[64];
    __shared__ float lds_g[256];

    float whh[64], wih[64];
#pragma unroll
    for (int k = 0; k < 64; k += 4) {
        float4 v = *reinterpret_cast<const float4*>(&Whh[t * 64 + k]);
        whh[k] = v.x; whh[k+1] = v.y; whh[k+2] = v.z; whh[k+3] = v.w;
        float4 u = *reinterpret_cast<const float4*>(&Wih[t * 64 + k]);
        wih[k] = u.x; wih[k+1] = u.y; wih[k+2] = u.z; wih[k+3] = u.w;
    }
    const float bias = bih[t] + bhh[t];
    float c = 0.0f;
    if (t < 64) lds_h[t] = 0.0f;
    __syncthreads();

#pragma unroll 1
    for (int step = 0; step < 8; ++step) {
        if (t < 64) lds_x[t] = dist_hist[(b*8 + step)*64 + t];
        __syncthreads();
        float acc = bias;
#pragma unroll
        for (int k = 0; k < 64; k += 4) {
            float4 h4 = *reinterpret_cast<const float4*>(&lds_h[k]);
            float4 x4 = *reinterpret_cast<const float4*>(&lds_x[k]);
            acc += whh[k]*h4.x + whh[k+1]*h4.y + whh[k+2]*h4.z + whh[k+3]*h4.w;
            acc += wih[k]*x4.x + wih[k+1]*x4.y + wih[k+2]*x4.z + wih[k+3]*x4.w;
        }
        const float gv = ((t >> 6) == 2) ? (2.0f / (1.0f + __expf(-2.0f*acc)) - 1.0f)
                                         : (1.0f / (1.0f + __expf(-acc)));
        lds_g[t] = gv;
        __syncthreads();
        if (t < 64) {
            const float gi = lds_g[t], gf = lds_g[64+t], gc = lds_g[128+t], go = lds_g[192+t];
            c = gf * c + gi * gc;
            const float h = go * (2.0f / (1.0f + __expf(-2.0f*c)) - 1.0f);
            lds_h[t] = h;
            out[(b*8 + step)*64 + t] = h;
        }
        __syncthreads();
    }
}

// ---------------------------------------------------------------------------
// Kernel 4: decoder LSTM + pose head (unchanged). In=128, H=32, T=8.
// ---------------------------------------------------------------------------
__global__ __launch_bounds__(128) void dec_lstm_k(
    const float* __restrict__ lstm_out, const float* __restrict__ full_dist,
    const float* __restrict__ scene, const float* __restrict__ Wih,
    const float* __restrict__ Whh, const float* __restrict__ bih,
    const float* __restrict__ bhh, const float* __restrict__ pose_W,
    const float* __restrict__ pose_b, float* __restrict__ out)
{
    const int b = blockIdx.x;
    const int t = threadIdx.x;
    __shared__ __align__(16) float lds_h[32];
    __shared__ __align__(16) float lds_x[128];
    __shared__ float lds_g[128];
    __shared__ float lds_dec[8][32];

    float wih[128];
#pragma unroll
    for (int k = 0; k < 128; k += 4) {
        float4 u = *reinterpret_cast<const float4*>(&Wih[t * 128 + k]);
        wih[k] = u.x; wih[k+1] = u.y; wih[k+2] = u.z; wih[k+3] = u.w;
    }
    float whh[32];
#pragma unroll
    for (int k = 0; k < 32; k += 4) {
        float4 v = *reinterpret_cast<const float4*>(&Whh[t * 32 + k]);
        whh[k] = v.x; whh[k+1] = v.y; whh[k+2] = v.z; whh[k+3] = v.w;
    }
    const float bias = bih[t] + bhh[t];
    float c = 0.0f;
    if (t < 32) lds_h[t] = 0.0f;
    __syncthreads();

#pragma unroll 1
    for (int step = 0; step < 8; ++step) {
        if (t < 64) lds_x[t] = lstm_out[(b*8 + step)*64 + t];
        else        lds_x[t] = full_dist[(b*8 + step)*64 + (t - 64)];
        __syncthreads();
        float acc = bias;
#pragma unroll
        for (int k = 0; k < 128; k += 4) {
            float4 x4 = *reinterpret_cast<const float4*>(&lds_x[k]);
            acc += wih[k]*x4.x + wih[k+1]*x4.y + wih[k+2]*x4.z + wih[k+3]*x4.w;
        }
#pragma unroll
        for (int k = 0; k < 32; k += 4) {
            float4 h4 = *reinterpret_cast<const float4*>(&lds_h[k]);
            acc += whh[k]*h4.x + whh[k+1]*h4.y + whh[k+2]*h4.z + whh[k+3]*h4.w;
        }
        const float gv = ((t >> 5) == 2) ? (2.0f / (1.0f + __expf(-2.0f*acc)) - 1.0f)
                                         : (1.0f / (1.0f + __expf(-acc)));
        lds_g[t] = gv;
        __syncthreads();
        if (t < 32) {
            const float gi = lds_g[t], gf = lds_g[32+t], gc = lds_g[64+t], go = lds_g[96+t];
            c = gf * c + gi * gc;
            const float h = go * (2.0f / (1.0f + __expf(-2.0f*c)) - 1.0f);
            lds_h[t] = h;
            lds_dec[step][t] = h;
        }
        __syncthreads();
    }

    if (t < 2) {
        const float* dec_flat = &lds_dec[0][0];
        float acc = scene[b*16 + 14 + t] + pose_b[t];
        for (int q = 0; q < 256; ++q)
            acc += dec_flat[q] * pose_W[t*256 + q];
        out[b*2 + t] = acc;
    }
}

// ---------------------------------------------------------------------------
extern "C" void kernel_launch(void* const* d_in, const int* in_sizes, int n_in,
                              void* d_out, int out_size, void* d_ws, size_t ws_size,
                              hipStream_t stream) {
    const float* scene    = (const float*)d_in[0];
    const float* node_Wih = (const float*)d_in[1];
    const float* node_Whh = (const float*)d_in[2];
    const float* node_bih = (const float*)d_in[3];
    const float* node_bhh = (const float*)d_in[4];
    const float* edge_Wih = (const float*)d_in[5];
    const float* edge_Whh = (const float*)d_in[6];
    const float* edge_bih = (const float*)d_in[7];
    const float* edge_bhh = (const float*)d_in[8];
    const float* seq_Wih  = (const float*)d_in[9];
    const float* seq_Whh  = (const float*)d_in[10];
    const float* seq_bih  = (const float*)d_in[11];
    const float* seq_bhh  = (const float*)d_in[12];
    const float* dec_Wih  = (const float*)d_in[13];
    const float* dec_Whh  = (const float*)d_in[14];
    const float* dec_bih  = (const float*)d_in[15];
    const float* dec_bhh  = (const float*)d_in[16];
    const float* pose_W   = (const float*)d_in[17];
    const float* pose_b   = (const float*)d_in[18];
    float* out = (float*)d_out;

    float* ws = (float*)d_ws;
    float* lstm_out  = ws;               // 256*8*64
    float* dist_hist = ws + 131072;      // 256*8*64
    float* full_dist = ws + 262144;      // 256*8*64

    node_lstm_k<<<256, 256, 0, stream>>>(scene, node_Wih, node_Whh, node_bih, node_bhh, lstm_out);
    edge_lstm_mfma_k<<<128, 256, 0, stream>>>(scene, edge_Wih, edge_Whh, edge_bih, edge_bhh, dist_hist);
    seq_lstm_k<<<256, 256, 0, stream>>>(dist_hist, seq_Wih, seq_Whh, seq_bih, seq_bhh, full_dist);
    dec_lstm_k<<<256, 128, 0, stream>>>(lstm_out, full_dist, scene, dec_Wih, dec_Whh,
                                        dec_bih, dec_bhh, pose_W, pose_b, out);
}

// Round 3
// 148.515 us; speedup vs baseline: 2.7865x; 1.1648x over previous
//
#include <hip/hip_runtime.h>
#include <math.h>

#define DEVINL __device__ __forceinline__

typedef __attribute__((ext_vector_type(8))) short bf16x8;
typedef __attribute__((ext_vector_type(4))) float f32x4;

DEVINL float sigm(float x) { return __builtin_amdgcn_rcpf(1.0f + __expf(-x)); }
DEVINL float tanh_(float x) { return fmaf(2.0f, __builtin_amdgcn_rcpf(1.0f + __expf(-2.0f * x)), -1.0f); }

DEVINL unsigned short f2bf(float f) {
    union { float f; unsigned u; } v; v.f = f;
    unsigned r = v.u + 0x7FFFu + ((v.u >> 16) & 1u);   // RNE
    return (unsigned short)(r >> 16);
}

DEVINL bf16x8 pack8(const float* p) {
    bf16x8 r;
#pragma unroll
    for (int e = 0; e < 8; ++e) r[e] = (short)f2bf(p[e]);
    return r;
}

DEVINL unsigned cvt_pk_bf16(float lo, float hi) {
    unsigned r;
    asm("v_cvt_pk_bf16_f32 %0, %1, %2" : "=v"(r) : "v"(lo), "v"(hi));
    return r;   // low 16 = bf16(lo), high 16 = bf16(hi)
}

DEVINL float swz8(float x) {   // value from lane^8
    int r = __builtin_amdgcn_ds_swizzle(__builtin_bit_cast(int, x), 0x201F); // xor=8
    return __builtin_bit_cast(float, r);
}

// ---------------------------------------------------------------------------
// Fused kernel: blocks [0,256) = edge LSTM (8 seqs each: person i, s=0..7),
//               blocks [256,512) = node LSTM (1 batch row each).
//
// Edge per block: 4 waves (wave w = u-group [16w,16w+16)). Per step j:
//   acc[q] = mfma(A1,B1, mfma(A0,B0, base[q]))      base = bias - Wih*scene_i
//   ds_swizzle xor-8 rebalances the 8 valid cols -> 2 updates per lane
//   + Wih*scene_j term, activations, cvt_pk -> bf16 h, swizzled LDS write
// One barrier per step, double-buffered 1KB h tiles.
// ---------------------------------------------------------------------------
__global__ __launch_bounds__(256, 1) void fused_node_edge_k(
    const float* __restrict__ scene,      // [256][8][2]
    const float* __restrict__ eWih, const float* __restrict__ eWhh,
    const float* __restrict__ ebih, const float* __restrict__ ebhh,
    const float* __restrict__ nWih, const float* __restrict__ nWhh,
    const float* __restrict__ nbih, const float* __restrict__ nbhh,
    float* __restrict__ dist_hist,        // [2048][64]
    float* __restrict__ lstm_out)         // [256][8][64]
{
    __shared__ __align__(16) float lds_scene[256 * 16];        // 16 KB (edge)
    __shared__ __align__(16) unsigned short hbuf[2][8 * 64];   // 2 KB  (edge)
    __shared__ __align__(16) float lds_h[64];                  // (node)
    __shared__ float lds_g[256];                               // (node)

    const int t = threadIdx.x;

    if (blockIdx.x < 256) {
        // ================= EDGE =================
        const int i    = blockIdx.x;
        const int w    = t >> 6;         // wave -> u-group
        const int l    = t & 63;
        const int lg   = l >> 4;         // 0..3
        const int nc   = l & 15;         // MFMA col
        const int n    = l & 7;          // timestep s (worker + masked B col)
        const int half = (l >> 3) & 1;

        // stage scene (coalesced float4), zero both h buffers
        {
            const float4* src = reinterpret_cast<const float4*>(scene);
            float4* dst = reinterpret_cast<float4*>(lds_scene);
#pragma unroll
            for (int k = 0; k < 4; ++k) dst[k * 256 + t] = src[k * 256 + t];
            unsigned* z = reinterpret_cast<unsigned*>(&hbuf[0][0]);
            z[t] = 0u; z[t + 256] = 0u;
        }

        // A fragments: row = 64q + 16w + nc, k = 32*kt + 8*lg + e
        bf16x8 afrag[4][2];
#pragma unroll
        for (int q = 0; q < 4; ++q) {
            const int arow = 64 * q + 16 * w + nc;
#pragma unroll
            for (int kt = 0; kt < 2; ++kt) {
                float tmp[8];
                float4 v0 = *reinterpret_cast<const float4*>(&eWhh[arow * 64 + kt * 32 + lg * 8]);
                float4 v1 = *reinterpret_cast<const float4*>(&eWhh[arow * 64 + kt * 32 + lg * 8 + 4]);
                tmp[0]=v0.x; tmp[1]=v0.y; tmp[2]=v0.z; tmp[3]=v0.w;
                tmp[4]=v1.x; tmp[5]=v1.y; tmp[6]=v1.z; tmp[7]=v1.w;
                afrag[q][kt] = pack8(tmp);
            }
        }

        // C-in base: bias - Wih*scene_i  (per pre-swizzle (q,r) slot)
        const float sxi = scene[i * 16 + (nc & 7) * 2 + 0];
        const float syi = scene[i * 16 + (nc & 7) * 2 + 1];
        f32x4 base[4];
#pragma unroll
        for (int q = 0; q < 4; ++q)
#pragma unroll
            for (int r = 0; r < 4; ++r) {
                const int g = 64 * q + 16 * w + 4 * lg + r;
                base[q][r] = ebih[g] + ebhh[g] - eWih[2*g] * sxi - eWih[2*g + 1] * syi;
            }

        // worker-side Wih for its 2 updates (u = 16w+4lg+2half+slot)
        float wxw[4][2], wyw[4][2];
#pragma unroll
        for (int q = 0; q < 4; ++q)
#pragma unroll
            for (int sl = 0; sl < 2; ++sl) {
                const int g = 64 * q + 16 * w + 4 * lg + 2 * half + sl;
                wxw[q][sl] = eWih[2*g];
                wyw[q][sl] = eWih[2*g + 1];
            }

        // LDS byte addrs. storage u' = u ^ (8n); row = 128B
        const int rdA = n * 128 + 2 * ((32 * (0 ^ (n >> 2))) + 8 * (lg ^ (n & 3)));
        const int rdB = n * 128 + 2 * ((32 * (1 ^ (n >> 2))) + 8 * (lg ^ (n & 3)));
        const int u0  = 16 * w + 4 * lg + 2 * half;
        const int wrb = n * 128 + 2 * (u0 ^ (n << 3));

        float c[2] = {0.f, 0.f};
        float h[2] = {0.f, 0.f};
        int cur = 0;
        __syncthreads();

#pragma unroll 1
        for (int j = 0; j < 256; ++j) {
            const char* hb = reinterpret_cast<const char*>(&hbuf[0][0]) + cur * 1024;
            bf16x8 b0 = *reinterpret_cast<const bf16x8*>(hb + rdA);
            bf16x8 b1 = *reinterpret_cast<const bf16x8*>(hb + rdB);
            float2 sc = *reinterpret_cast<const float2*>(&lds_scene[j * 16 + n * 2]);

            f32x4 acc[4];
#pragma unroll
            for (int q = 0; q < 4; ++q) {
                acc[q] = __builtin_amdgcn_mfma_f32_16x16x32_bf16(afrag[q][0], b0, base[q], 0, 0, 0);
                acc[q] = __builtin_amdgcn_mfma_f32_16x16x32_bf16(afrag[q][1], b1, acc[q], 0, 0, 0);
            }

            // rebalance: this lane's 2 updates' gate pre-activations
            float g0[4], g1[4];
#pragma unroll
            for (int q = 0; q < 4; ++q) {
                const float s2 = swz8(acc[q][2]);
                const float s3 = swz8(acc[q][3]);
                g0[q] = half ? s2 : acc[q][0];
                g1[q] = half ? s3 : acc[q][1];
            }
            // + Wih * scene_j
#pragma unroll
            for (int q = 0; q < 4; ++q) {
                g0[q] = fmaf(wyw[q][0], sc.y, fmaf(wxw[q][0], sc.x, g0[q]));
                g1[q] = fmaf(wyw[q][1], sc.y, fmaf(wxw[q][1], sc.x, g1[q]));
            }

            {
                const float gi = sigm(g0[0]), gf = sigm(g0[1]);
                const float gg = tanh_(g0[2]), go = sigm(g0[3]);
                c[0] = fmaf(gf, c[0], gi * gg);
                h[0] = go * tanh_(c[0]);
            }
            {
                const float gi = sigm(g1[0]), gf = sigm(g1[1]);
                const float gg = tanh_(g1[2]), go = sigm(g1[3]);
                c[1] = fmaf(gf, c[1], gi * gg);
                h[1] = go * tanh_(c[1]);
            }

            char* hw = reinterpret_cast<char*>(&hbuf[0][0]) + (cur ^ 1) * 1024;
            *reinterpret_cast<unsigned*>(hw + wrb) = cvt_pk_bf16(h[0], h[1]);

            __syncthreads();
            cur ^= 1;
        }

        // final h (f32) -> dist_hist[(i*8+n)][u0..u0+1]
        *reinterpret_cast<float2*>(&dist_hist[(i * 8 + n) * 64 + u0]) = make_float2(h[0], h[1]);

    } else {
        // ================= NODE =================
        const int b = blockIdx.x - 256;
        float whh[64];
#pragma unroll
        for (int k = 0; k < 64; k += 4) {
            float4 v = *reinterpret_cast<const float4*>(&nWhh[t * 64 + k]);
            whh[k] = v.x; whh[k+1] = v.y; whh[k+2] = v.z; whh[k+3] = v.w;
        }
        const float wx = nWih[2*t], wy = nWih[2*t + 1];
        const float bias = nbih[t] + nbhh[t];
        float c = 0.0f;
        if (t < 64) lds_h[t] = 0.0f;
        __syncthreads();

#pragma unroll 1
        for (int step = 0; step < 8; ++step) {
            const float x0 = scene[b*16 + step*2 + 0];
            const float x1 = scene[b*16 + step*2 + 1];
            float acc = wx * x0 + wy * x1 + bias;
#pragma unroll
            for (int k = 0; k < 64; k += 4) {
                float4 h4 = *reinterpret_cast<const float4*>(&lds_h[k]);
                acc += whh[k]*h4.x + whh[k+1]*h4.y + whh[k+2]*h4.z + whh[k+3]*h4.w;
            }
            const float gv = ((t >> 6) == 2) ? tanh_(acc) : sigm(acc);
            lds_g[t] = gv;
            __syncthreads();
            if (t < 64) {
                const float gi = lds_g[t], gf = lds_g[64+t], gc = lds_g[128+t], go = lds_g[192+t];
                c = gf * c + gi * gc;
                const float h = go * tanh_(c);
                lds_h[t] = h;
                lstm_out[(b*8 + step)*64 + t] = h;
            }
            __syncthreads();
        }
    }
}

// ---------------------------------------------------------------------------
// seq LSTM. B=256, T=8, In=64, H=64.
// ---------------------------------------------------------------------------
__global__ __launch_bounds__(256) void seq_lstm_k(
    const float* __restrict__ dist_hist, const float* __restrict__ Wih,
    const float* __restrict__ Whh, const float* __restrict__ bih,
    const float* __restrict__ bhh, float* __restrict__ out)
{
    const int b = blockIdx.x;
    const int t = threadIdx.x;
    __shared__ __align__(16) float lds_h[64];
    __shared__ __align__(16) float lds_x[64];
    __shared__ float lds_g[256];

    float whh[64], wih[64];
#pragma unroll
    for (int k = 0; k < 64; k += 4) {
        float4 v = *reinterpret_cast<const float4*>(&Whh[t * 64 + k]);
        whh[k] = v.x; whh[k+1] = v.y; whh[k+2] = v.z; whh[k+3] = v.w;
        float4 u = *reinterpret_cast<const float4*>(&Wih[t * 64 + k]);
        wih[k] = u.x; wih[k+1] = u.y; wih[k+2] = u.z; wih[k+3] = u.w;
    }
    const float bias = bih[t] + bhh[t];
    float c = 0.0f;
    if (t < 64) lds_h[t] = 0.0f;
    __syncthreads();

#pragma unroll 1
    for (int step = 0; step < 8; ++step) {
        if (t < 64) lds_x[t] = dist_hist[(b*8 + step)*64 + t];
        __syncthreads();
        float acc = bias;
#pragma unroll
        for (int k = 0; k < 64; k += 4) {
            float4 h4 = *reinterpret_cast<const float4*>(&lds_h[k]);
            float4 x4 = *reinterpret_cast<const float4*>(&lds_x[k]);
            acc += whh[k]*h4.x + whh[k+1]*h4.y + whh[k+2]*h4.z + whh[k+3]*h4.w;
            acc += wih[k]*x4.x + wih[k+1]*x4.y + wih[k+2]*x4.z + wih[k+3]*x4.w;
        }
        const float gv = ((t >> 6) == 2) ? tanh_(acc) : sigm(acc);
        lds_g[t] = gv;
        __syncthreads();
        if (t < 64) {
            const float gi = lds_g[t], gf = lds_g[64+t], gc = lds_g[128+t], go = lds_g[192+t];
            c = gf * c + gi * gc;
            const float h = go * tanh_(c);
            lds_h[t] = h;
            out[(b*8 + step)*64 + t] = h;
        }
        __syncthreads();
    }
}

// ---------------------------------------------------------------------------
// decoder LSTM + pose head. In=128, H=32, T=8.
// ---------------------------------------------------------------------------
__global__ __launch_bounds__(128) void dec_lstm_k(
    const float* __restrict__ lstm_out, const float* __restrict__ full_dist,
    const float* __restrict__ scene, const float* __restrict__ Wih,
    const float* __restrict__ Whh, const float* __restrict__ bih,
    const float* __restrict__ bhh, const float* __restrict__ pose_W,
    const float* __restrict__ pose_b, float* __restrict__ out)
{
    const int b = blockIdx.x;
    const int t = threadIdx.x;
    __shared__ __align__(16) float lds_h[32];
    __shared__ __align__(16) float lds_x[128];
    __shared__ float lds_g[128];
    __shared__ float lds_dec[8][32];

    float wih[128];
#pragma unroll
    for (int k = 0; k < 128; k += 4) {
        float4 u = *reinterpret_cast<const float4*>(&Wih[t * 128 + k]);
        wih[k] = u.x; wih[k+1] = u.y; wih[k+2] = u.z; wih[k+3] = u.w;
    }
    float whh[32];
#pragma unroll
    for (int k = 0; k < 32; k += 4) {
        float4 v = *reinterpret_cast<const float4*>(&Whh[t * 32 + k]);
        whh[k] = v.x; whh[k+1] = v.y; whh[k+2] = v.z; whh[k+3] = v.w;
    }
    const float bias = bih[t] + bhh[t];
    float c = 0.0f;
    if (t < 32) lds_h[t] = 0.0f;
    __syncthreads();

#pragma unroll 1
    for (int step = 0; step < 8; ++step) {
        if (t < 64) lds_x[t] = lstm_out[(b*8 + step)*64 + t];
        else        lds_x[t] = full_dist[(b*8 + step)*64 + (t - 64)];
        __syncthreads();
        float acc = bias;
#pragma unroll
        for (int k = 0; k < 128; k += 4) {
            float4 x4 = *reinterpret_cast<const float4*>(&lds_x[k]);
            acc += wih[k]*x4.x + wih[k+1]*x4.y + wih[k+2]*x4.z + wih[k+3]*x4.w;
        }
#pragma unroll
        for (int k = 0; k < 32; k += 4) {
            float4 h4 = *reinterpret_cast<const float4*>(&lds_h[k]);
            acc += whh[k]*h4.x + whh[k+1]*h4.y + whh[k+2]*h4.z + whh[k+3]*h4.w;
        }
        const float gv = ((t >> 5) == 2) ? tanh_(acc) : sigm(acc);
        lds_g[t] = gv;
        __syncthreads();
        if (t < 32) {
            const float gi = lds_g[t], gf = lds_g[32+t], gc = lds_g[64+t], go = lds_g[96+t];
            c = gf * c + gi * gc;
            const float h = go * tanh_(c);
            lds_h[t] = h;
            lds_dec[step][t] = h;
        }
        __syncthreads();
    }

    if (t < 2) {
        const float* dec_flat = &lds_dec[0][0];
        float acc = scene[b*16 + 14 + t] + pose_b[t];
        for (int q = 0; q < 256; ++q)
            acc += dec_flat[q] * pose_W[t*256 + q];
        out[b*2 + t] = acc;
    }
}

// ---------------------------------------------------------------------------
extern "C" void kernel_launch(void* const* d_in, const int* in_sizes, int n_in,
                              void* d_out, int out_size, void* d_ws, size_t ws_size,
                              hipStream_t stream) {
    const float* scene    = (const float*)d_in[0];
    const float* node_Wih = (const float*)d_in[1];
    const float* node_Whh = (const float*)d_in[2];
    const float* node_bih = (const float*)d_in[3];
    const float* node_bhh = (const float*)d_in[4];
    const float* edge_Wih = (const float*)d_in[5];
    const float* edge_Whh = (const float*)d_in[6];
    const float* edge_bih = (const float*)d_in[7];
    const float* edge_bhh = (const float*)d_in[8];
    const float* seq_Wih  = (const float*)d_in[9];
    const float* seq_Whh  = (const float*)d_in[10];
    const float* seq_bih  = (const float*)d_in[11];
    const float* seq_bhh  = (const float*)d_in[12];
    const float* dec_Wih  = (const float*)d_in[13];
    const float* dec_Whh  = (const float*)d_in[14];
    const float* dec_bih  = (const float*)d_in[15];
    const float* dec_bhh  = (const float*)d_in[16];
    const float* pose_W   = (const float*)d_in[17];
    const float* pose_b   = (const float*)d_in[18];
    float* out = (float*)d_out;

    float* ws = (float*)d_ws;
    float* lstm_out  = ws;               // 256*8*64
    float* dist_hist = ws + 131072;      // 256*8*64
    float* full_dist = ws + 262144;      // 256*8*64

    fused_node_edge_k<<<512, 256, 0, stream>>>(scene,
        edge_Wih, edge_Whh, edge_bih, edge_bhh,
        node_Wih, node_Whh, node_bih, node_bhh,
        dist_hist, lstm_out);
    seq_lstm_k<<<256, 256, 0, stream>>>(dist_hist, seq_Wih, seq_Whh, seq_bih, seq_bhh, full_dist);
    dec_lstm_k<<<256, 128, 0, stream>>>(lstm_out, full_dist, scene, dec_Wih, dec_Whh,
                                        dec_bih, dec_bhh, pose_W, pose_b, out);
}